// Round 10
// baseline (344.897 us; speedup 1.0000x reference)
//
#include <hip/hip_runtime.h>
#include <hip/hip_bf16.h>
#include <math.h>

// Problem constants (fixed by setup_inputs)
#define BB 4
#define NN 16384
#define SS 4096
#define D1 128
#define D2 256
#define C1 256   // mlp[0]
#define C2 128   // mlp[1]
#define MTOT (BB*NN)   // 65536

// knn decomposition (R8: NCH=16; R15: 128-thr blocks; R16: 8-wide register
// load batches + sched_barrier(0) -> LDS latency exposed 1/8 as often.
// R9 counters: VGPR=20 proved the compiler emitted load;wait;body per iter.)
#define QPT 2              // queries per thread
#define SCH 256            // candidates per chunk (4KB LDS)
#define NCH (SS/SCH)       // 16 chunks
#define PTH 128            // threads per partial block
#define LB  8              // load batch width (8 x float4 = 32 VGPR)

typedef _Float16 f16x8 __attribute__((ext_vector_type(8)));
typedef float f32x4  __attribute__((ext_vector_type(4)));
typedef int   i32x4  __attribute__((ext_vector_type(4)));

#define LPAD 40            // LDS row stride in fp16 elems (80B, 16B-aligned)

// ---------------------------------------------------------------------------
// Pack xyz2 into float4 {-2x, -2y, -2z, ||p||^2} (bit-exact vs reference:
// x(-2) is exact pow2 scaling, so (qq + cr2) + pw == (qq - 2*cr) + pw).
// ---------------------------------------------------------------------------
__global__ __launch_bounds__(256) void pack_kernel(
    const float* __restrict__ xyz2, float4* __restrict__ packed)
{
#pragma clang fp contract(off)
    int s = blockIdx.x * 256 + threadIdx.x;
    float px = xyz2[s*3+0], py = xyz2[s*3+1], pz = xyz2[s*3+2];
    float pp = (px*px + py*py) + pz*pz;
    packed[s] = make_float4(-2.0f*px, -2.0f*py, -2.0f*pz, pp);
}

// ---------------------------------------------------------------------------
// Convert W1, W2 to fp16 (RNE) once.
// ---------------------------------------------------------------------------
__global__ __launch_bounds__(256) void wcvt_kernel(
    const float* __restrict__ W1, const float* __restrict__ W2,
    _Float16* __restrict__ W1c, _Float16* __restrict__ W2c)
{
    int i = blockIdx.x * 256 + threadIdx.x;
    if (i < C1 * (D1 + D2)) W1c[i] = (_Float16)W1[i];
    if (i < C2 * C1)        W2c[i] = (_Float16)W2[i];
}

// ---------------------------------------------------------------------------
// 3-NN pass 1: exact fp32 distances (contract off), min/med3 distance chain +
// cndmask index chain, strict '<' with ascending candidate order (stable,
// == lax.top_k). HARD CONSTRAINT (R7): selection is discontinuous in the
// gathered features -> never approximate the distance or the comparison.
// R16: 8-wide register load batch + sched_barrier(0) between load cluster
// and compute cluster (m214-r263 pattern) so the compiler cannot re-serialize
// the ds_reads; one exposed LDS latency per ~640 issue-cycles.
// ---------------------------------------------------------------------------
__global__ __launch_bounds__(PTH, 8) void knn3_partial_kernel(
    const float* __restrict__ xyz1, const float4* __restrict__ packed,
    float* __restrict__ pd0, float* __restrict__ pd1, float* __restrict__ pd2,
    int* __restrict__ pi0, int* __restrict__ pi1, int* __restrict__ pi2)
{
#pragma clang fp contract(off)
    __shared__ float4 pk[SCH];                       // 4 KB

    const int qblocks = NN / (PTH * QPT);            // 64
    const int b  = blockIdx.x / (qblocks * NCH);
    const int r  = blockIdx.x % (qblocks * NCH);
    const int qc = r / NCH;
    const int sc = r % NCH;

    const float4* src = packed + (size_t)b * SS + sc * SCH;
    for (int i = threadIdx.x; i < SCH; i += PTH) pk[i] = src[i];
    __syncthreads();

    float qx[QPT], qy[QPT], qz[QPT], qq[QPT];
    float e0[QPT], e1[QPT], e2[QPT];
    int   j0[QPT], j1[QPT], j2[QPT];
#pragma unroll
    for (int q = 0; q < QPT; ++q) {
        int n = qc * (PTH * QPT) + q * PTH + threadIdx.x;
        size_t m = (size_t)b * NN + n;
        qx[q] = xyz1[m*3+0]; qy[q] = xyz1[m*3+1]; qz[q] = xyz1[m*3+2];
        qq[q] = (qx[q]*qx[q] + qy[q]*qy[q]) + qz[q]*qz[q];
        e0[q] = 3.4e38f; e1[q] = 3.4e38f; e2[q] = 3.4e38f;
        j0[q] = 0; j1[q] = 0; j2[q] = 0;
    }

    auto proc = [&](float4 p, int s) {
#pragma clang fp contract(off)
#pragma unroll
        for (int q = 0; q < QPT; ++q) {
            float cr2 = (qx[q]*p.x + qy[q]*p.y) + qz[q]*p.z;   // == -2*cr exactly
            float d = (qq[q] + cr2) + p.w;
            d = fmaxf(d, 0.0f);
            bool c0 = d < e0[q], c1 = d < e1[q], c2 = d < e2[q];
            j2[q] = c1 ? j1[q] : (c2 ? s : j2[q]);
            j1[q] = c0 ? j0[q] : (c1 ? s : j1[q]);
            j0[q] = c0 ? s : j0[q];
            e2[q] = __builtin_amdgcn_fmed3f(e1[q], d, e2[q]);
            e1[q] = __builtin_amdgcn_fmed3f(e0[q], d, e1[q]);
            e0[q] = fminf(e0[q], d);
        }
    };

    for (int s = 0; s < SCH; s += LB) {
        float4 P[LB];
#pragma unroll
        for (int i = 0; i < LB; ++i) P[i] = pk[s + i];   // 8 x ds_read_b128
        __builtin_amdgcn_sched_barrier(0);               // pin loads before bodies
#pragma unroll
        for (int i = 0; i < LB; ++i) proc(P[i], s + i);
    }

#pragma unroll
    for (int q = 0; q < QPT; ++q) {
        int n = qc * (PTH * QPT) + q * PTH + threadIdx.x;
        size_t m = (size_t)b * NN + n;
        size_t o = (size_t)sc * MTOT + m;
        pd0[o] = e0[q]; pd1[o] = e1[q]; pd2[o] = e2[q];
        pi0[o] = sc*SCH + j0[q];
        pi1[o] = sc*SCH + j1[q];
        pi2[o] = sc*SCH + j2[q];
    }
}

// ---------------------------------------------------------------------------
// 3-NN pass 2: merge chunk triples (ascending chunk order, ascending j within
// chunk, strict '<') — identical scan order to a full ascending pass.
// SoA planes -> all loads lane-coalesced and mutually independent.
// ---------------------------------------------------------------------------
__global__ __launch_bounds__(256) void knn3_merge_kernel(
    const float* __restrict__ pd0, const float* __restrict__ pd1, const float* __restrict__ pd2,
    const int* __restrict__ pi0, const int* __restrict__ pi1, const int* __restrict__ pi2,
    int* __restrict__ idx_out, float* __restrict__ w_out)
{
#pragma clang fp contract(off)
    int m = blockIdx.x * 256 + threadIdx.x;
    int b = m / NN;

    float d0 = pd0[m], d1 = pd1[m], d2 = pd2[m];
    int   i0 = pi0[m], i1 = pi1[m], i2 = pi2[m];

#pragma unroll
    for (int c = 1; c < NCH; ++c) {
        size_t oc = (size_t)c * MTOT + m;
        float da = pd0[oc], db = pd1[oc], dc = pd2[oc];
        int   sa = pi0[oc], sb = pi1[oc], scv = pi2[oc];
        {
            float d = da; int s = sa;
            bool c0 = d < d0, c1 = d < d1, c2 = d < d2;
            d2 = c1 ? d1 : (c2 ? d : d2);  i2 = c1 ? i1 : (c2 ? s : i2);
            d1 = c0 ? d0 : (c1 ? d : d1);  i1 = c0 ? i0 : (c1 ? s : i1);
            d0 = c0 ? d : d0;              i0 = c0 ? s : i0;
        }
        {
            float d = db; int s = sb;
            bool c0 = d < d0, c1 = d < d1, c2 = d < d2;
            d2 = c1 ? d1 : (c2 ? d : d2);  i2 = c1 ? i1 : (c2 ? s : i2);
            d1 = c0 ? d0 : (c1 ? d : d1);  i1 = c0 ? i0 : (c1 ? s : i1);
            d0 = c0 ? d : d0;              i0 = c0 ? s : i0;
        }
        {
            float d = dc; int s = scv;
            bool c0 = d < d0, c1 = d < d1, c2 = d < d2;
            d2 = c1 ? d1 : (c2 ? d : d2);  i2 = c1 ? i1 : (c2 ? s : i2);
            d1 = c0 ? d0 : (c1 ? d : d1);  i1 = c0 ? i0 : (c1 ? s : i1);
            d0 = c0 ? d : d0;              i0 = c0 ? s : i0;
        }
    }
    float r0 = 1.0f / (d0 + 1e-8f);
    float r1 = 1.0f / (d1 + 1e-8f);
    float r2 = 1.0f / (d2 + 1e-8f);
    float inv = 1.0f / ((r0 + r1) + r2);
    idx_out[m*3+0] = b * SS + i0;
    idx_out[m*3+1] = b * SS + i1;
    idx_out[m*3+2] = b * SS + i2;
    w_out[m*3+0] = r0 * inv;
    w_out[m*3+1] = r1 * inv;
    w_out[m*3+2] = r2 * inv;
}

// ---------------------------------------------------------------------------
// fp16 MFMA GEMM, LDS double-buffered with ONE barrier per k-iter.
// C[M x N] = op(A[M x K]) @ W[N x K]^T (+ bias).
// Tile 64(M) x 128(N), 4 waves of 32x64, k-chunk 32 (16x16x32 f16 MFMA).
// ---------------------------------------------------------------------------
template<int K, typename AT, typename OT, bool BN_A, bool FUSE_STATS>
__global__ __launch_bounds__(256, 4) void gemm_mfma_kernel(
    const AT* __restrict__ A, int lda,
    const _Float16* __restrict__ W, int ldw,
    OT* __restrict__ C, int ldc,
    const float* __restrict__ bias,
    const float* __restrict__ scaleA, const float* __restrict__ shiftA,
    float* __restrict__ sumO, float* __restrict__ sqO)
{
    __shared__ _Float16 Ash[2][64 * LPAD];     // 2 x 5 KB
    __shared__ _Float16 Bsh[2][128 * LPAD];    // 2 x 10 KB

    const int tid = threadIdx.x;
    const int m0 = blockIdx.x * 64;
    const int n0 = blockIdx.y * 128;
    const int wave = tid >> 6, lane = tid & 63;
    const int ln = lane & 15, q4 = lane >> 4;
    const int wm = wave & 1, wn = wave >> 1;

    const int ar = tid >> 2, ak = (tid & 3) * 8;   // A staging: 64 rows x 32k
    const int br = tid >> 1, bk = (tid & 1) * 16;  // B staging: 128 rows x 32k

    f32x4 acc[2][4] = {};

    float  avF[8];      // used when AT == float
    f16x8  avH;         // used when AT == _Float16
    f16x8  bvA[2];

    {   // prologue prefetch k0 = 0
        if constexpr (__is_same(AT, float)) {
            const float* ap = A + (size_t)(m0 + ar) * lda + ak;
            *(float4*)&avF[0] = *(const float4*)ap;
            *(float4*)&avF[4] = *(const float4*)(ap + 4);
        } else {
            avH = *(const f16x8*)(A + (size_t)(m0 + ar) * lda + ak);
        }
        const _Float16* bp = W + (size_t)(n0 + br) * ldw + bk;
        bvA[0] = *(const f16x8*)bp;
        bvA[1] = *(const f16x8*)(bp + 8);
    }

    for (int k0 = 0; k0 < K; k0 += 32) {
        const int buf = (k0 >> 5) & 1;

        // ---- transform + store staged regs to LDS[buf] ----
        {
            float av[8];
            if constexpr (__is_same(AT, float)) {
#pragma unroll
                for (int i = 0; i < 8; ++i) av[i] = avF[i];
            } else {
#pragma unroll
                for (int i = 0; i < 8; ++i) av[i] = (float)avH[i];
            }
            if (BN_A) {
#pragma unroll
                for (int i = 0; i < 8; ++i) {
                    float sc = scaleA[k0 + ak + i];
                    float sh = shiftA[k0 + ak + i];
                    av[i] = fmaxf(av[i] * sc + sh, 0.0f);
                }
            }
            f16x8 vh;
#pragma unroll
            for (int i = 0; i < 8; ++i) vh[i] = (_Float16)av[i];
            *(f16x8*)&Ash[buf][ar * LPAD + ak] = vh;
            *(f16x8*)&Bsh[buf][br * LPAD + bk]     = bvA[0];
            *(f16x8*)&Bsh[buf][br * LPAD + bk + 8] = bvA[1];
        }
        __syncthreads();    // single barrier: writers of buf done; dbuf makes it safe

        // ---- issue next chunk's global loads (overlap with MFMA below) ----
        if (k0 + 32 < K) {
            if constexpr (__is_same(AT, float)) {
                const float* ap = A + (size_t)(m0 + ar) * lda + (k0 + 32) + ak;
                *(float4*)&avF[0] = *(const float4*)ap;
                *(float4*)&avF[4] = *(const float4*)(ap + 4);
            } else {
                avH = *(const f16x8*)(A + (size_t)(m0 + ar) * lda + (k0 + 32) + ak);
            }
            const _Float16* bp = W + (size_t)(n0 + br) * ldw + (k0 + 32) + bk;
            bvA[0] = *(const f16x8*)bp;
            bvA[1] = *(const f16x8*)(bp + 8);
        }

        // ---- fragments + MFMA ----
        f16x8 af[2];
#pragma unroll
        for (int mi = 0; mi < 2; ++mi) {
            int arow = wm * 32 + mi * 16 + ln;
            af[mi] = *(const f16x8*)&Ash[buf][arow * LPAD + q4 * 8];
        }
        f16x8 bf[4];
#pragma unroll
        for (int ni = 0; ni < 4; ++ni) {
            int brow = wn * 64 + ni * 16 + ln;
            bf[ni] = *(const f16x8*)&Bsh[buf][brow * LPAD + q4 * 8];
        }
#pragma unroll
        for (int mi = 0; mi < 2; ++mi)
#pragma unroll
            for (int ni = 0; ni < 4; ++ni)
                acc[mi][ni] = __builtin_amdgcn_mfma_f32_16x16x32_f16(af[mi], bf[ni], acc[mi][ni], 0, 0, 0);
    }

    // ---- epilogue ----  C/D layout: col = ln, row = q4*4 + r  (m89/m91)
#pragma unroll
    for (int ni = 0; ni < 4; ++ni) {
        int col = n0 + wn * 64 + ni * 16 + ln;
        float vb = bias ? bias[col] : 0.0f;
        float s = 0.0f, s2 = 0.0f;
#pragma unroll
        for (int mi = 0; mi < 2; ++mi) {
#pragma unroll
            for (int r = 0; r < 4; ++r) {
                int row_g = m0 + wm * 32 + mi * 16 + q4 * 4 + r;
                float v = acc[mi][ni][r] + vb;
                C[(size_t)row_g * ldc + col] = (OT)v;
                s += v; s2 += v * v;
            }
        }
        if (FUSE_STATS) {
            s  += __shfl_xor(s, 16);  s  += __shfl_xor(s, 32);
            s2 += __shfl_xor(s2, 16); s2 += __shfl_xor(s2, 32);
            if (q4 == 0) {
                atomicAdd(&sumO[col], s);
                atomicAdd(&sqO[col], s2);
            }
        }
    }
}

// ---------------------------------------------------------------------------
// Dedicated interp + bias + BN1-stats kernel.
// y1[m, :] = temp[m, :] + wa*P2[ia, :] + wb*P2[ib, :] + wc*P2[ic, :] + b1
// ---------------------------------------------------------------------------
__global__ __launch_bounds__(256, 8) void interp_stats_kernel(
    const float* __restrict__ temp,     // [MTOT x C1] fp32 gemm result
    const _Float16* __restrict__ P2,    // [BB*SS x C1] f16
    const int* __restrict__ idx3, const float* __restrict__ w3,
    const float* __restrict__ bias,
    _Float16* __restrict__ Y,           // [MTOT x C1] f16
    float* __restrict__ sumO, float* __restrict__ sqO)
{
    __shared__ float sred[2 * C1];      // 512 floats: [sum | sumsq]
    const int tid = threadIdx.x;
    const int sl  = tid & 31;           // col slice (8 cols)
    const int rg  = tid >> 5;           // 0..7
    const int m0  = blockIdx.x * 32;

    sred[tid] = 0.0f; sred[tid + 256] = 0.0f;
    __syncthreads();

    float bv[8];
    *(float4*)&bv[0] = *(const float4*)(bias + sl * 8);
    *(float4*)&bv[4] = *(const float4*)(bias + sl * 8 + 4);

    float sAcc[8]  = {0.f,0.f,0.f,0.f,0.f,0.f,0.f,0.f};
    float s2Acc[8] = {0.f,0.f,0.f,0.f,0.f,0.f,0.f,0.f};

#pragma unroll
    for (int rr = 0; rr < 4; ++rr) {
        const int row = m0 + rg * 4 + rr;
        const int*   ip = idx3 + (size_t)row * 3;
        const float* wp = w3   + (size_t)row * 3;
        int   ia = ip[0], ib = ip[1], ic = ip[2];
        float wa = wp[0], wb = wp[1], wc = wp[2];

        float av[8];
        const float* tp = temp + (size_t)row * C1 + sl * 8;
        *(float4*)&av[0] = *(const float4*)tp;
        *(float4*)&av[4] = *(const float4*)(tp + 4);
        f16x8 pa = *(const f16x8*)(P2 + (size_t)ia * C1 + sl * 8);
        f16x8 pb = *(const f16x8*)(P2 + (size_t)ib * C1 + sl * 8);
        f16x8 pc = *(const f16x8*)(P2 + (size_t)ic * C1 + sl * 8);

        f16x8 outv;
#pragma unroll
        for (int i = 0; i < 8; ++i) {
            float v = av[i];
            v += wa * (float)pa[i];
            v += wb * (float)pb[i];
            v += wc * (float)pc[i];
            v += bv[i];
            outv[i] = (_Float16)v;
            sAcc[i]  += v;
            s2Acc[i] += v * v;
        }
        *(f16x8*)(Y + (size_t)row * C1 + sl * 8) = outv;
    }

#pragma unroll
    for (int i = 0; i < 8; ++i) {
        atomicAdd(&sred[sl * 8 + i],       sAcc[i]);
        atomicAdd(&sred[256 + sl * 8 + i], s2Acc[i]);
    }
    __syncthreads();
    atomicAdd(&sumO[tid], sred[tid]);
    atomicAdd(&sqO[tid],  sred[tid + 256]);
}

// ---------------------------------------------------------------------------
__global__ void finalize_kernel(
    const float* __restrict__ sum, const float* __restrict__ sumsq,
    const float* __restrict__ g, const float* __restrict__ beta,
    int M, int C, float* __restrict__ scale, float* __restrict__ shift)
{
    int c = threadIdx.x;
    if (c >= C) return;
    float invM = 1.0f / (float)M;
    float mean = sum[c] * invM;
    float var = fmaxf(sumsq[c] * invM - mean * mean, 0.0f);
    float rstd = 1.0f / sqrtf(var + 1e-5f);
    float sc = g[c] * rstd;
    scale[c] = sc;
    shift[c] = beta[c] - mean * sc;
}

__global__ __launch_bounds__(256) void bnrelu_kernel(
    float* __restrict__ X, int total4, int C,
    const float* __restrict__ scale, const float* __restrict__ shift)
{
    int i = blockIdx.x * 256 + threadIdx.x;
    if (i >= total4) return;
    float4 v = ((const float4*)X)[i];
    int c = (i * 4) & (C - 1);      // C pow2, 4 | C -> no wrap within the 4
    v.x = fmaxf(v.x * scale[c+0] + shift[c+0], 0.0f);
    v.y = fmaxf(v.y * scale[c+1] + shift[c+1], 0.0f);
    v.z = fmaxf(v.z * scale[c+2] + shift[c+2], 0.0f);
    v.w = fmaxf(v.w * scale[c+3] + shift[c+3], 0.0f);
    ((float4*)X)[i] = v;
}

// ---------------------------------------------------------------------------
extern "C" void kernel_launch(void* const* d_in, const int* in_sizes, int n_in,
                              void* d_out, int out_size, void* d_ws, size_t ws_size,
                              hipStream_t stream) {
    const float* xyz1    = (const float*)d_in[0];
    const float* xyz2    = (const float*)d_in[1];
    const float* points1 = (const float*)d_in[2];
    const float* points2 = (const float*)d_in[3];
    const float* W1      = (const float*)d_in[4];
    const float* b1      = (const float*)d_in[5];
    const float* g1      = (const float*)d_in[6];
    const float* beta1   = (const float*)d_in[7];
    const float* W2      = (const float*)d_in[8];
    const float* b2      = (const float*)d_in[9];
    const float* g2      = (const float*)d_in[10];
    const float* beta2   = (const float*)d_in[11];
    float* out = (float*)d_out;

    // ws layout (byte offsets, 16B-aligned)
    char* ws = (char*)d_ws;
    size_t off = 0;
    int*   idx = (int*)(ws + off);            off += (size_t)MTOT*3*4;
    float* w   = (float*)(ws + off);          off += (size_t)MTOT*3*4;
    _Float16* P2h = (_Float16*)(ws + off);    off += (size_t)BB*SS*C1*2;    // 8 MB
    _Float16* y1h = (_Float16*)(ws + off);    off += (size_t)MTOT*C1*2;     // 32 MB
    float* stats = (float*)(ws + off);        off += 2048*4;
    float* sum1 = stats;            // 256
    float* sq1  = stats + 256;      // 256
    float* sum2 = stats + 512;      // 128
    float* sq2  = stats + 640;      // 128
    float* scale1 = stats + 768;    // 256
    float* shift1 = stats + 1024;   // 256
    float* scale2 = stats + 1280;   // 128
    float* shift2 = stats + 1408;   // 128
    float4* packed = (float4*)(ws + off);     off += (size_t)BB*SS*16;      // 1 MB
    _Float16* W1c = (_Float16*)(ws + off);    off += (size_t)C1*(D1+D2)*2;
    _Float16* W2c = (_Float16*)(ws + off);    off += (size_t)C2*C1*2;
    off = (off + 255) & ~(size_t)255;
    float* tempf = (float*)(ws + off);        off += (size_t)MTOT*C1*4;     // 64 MB
    // knn partials: 6 SoA planes of NCH*MTOT (25.2 MB total) alias the y1h
    // region (32 MB; y1h is written later, by interp_stats_kernel)
    float* pd0 = (float*)y1h;                 // NCH*MTOT floats (4.2 MB each)
    float* pd1 = pd0 + (size_t)NCH*MTOT;
    float* pd2 = pd1 + (size_t)NCH*MTOT;
    int*   pi0 = (int*)(pd2 + (size_t)NCH*MTOT);
    int*   pi1 = pi0 + (size_t)NCH*MTOT;
    int*   pi2 = pi1 + (size_t)NCH*MTOT;

    hipMemsetAsync(stats, 0, 768 * sizeof(float), stream);

    pack_kernel<<<(BB*SS)/256, 256, 0, stream>>>(xyz2, packed);
    wcvt_kernel<<<(C1*(D1+D2))/256, 256, 0, stream>>>(W1, W2, W1c, W2c);

    knn3_partial_kernel<<<BB * (NN/(PTH*QPT)) * NCH, PTH, 0, stream>>>(
        xyz1, packed, pd0, pd1, pd2, pi0, pi1, pi2);
    knn3_merge_kernel<<<MTOT/256, 256, 0, stream>>>(
        pd0, pd1, pd2, pi0, pi1, pi2, idx, w);

    // P2 = points2 @ W1[:,128:]^T   [B*S x 256], K=256, f16 out
    gemm_mfma_kernel<256, float, _Float16, false, false>
        <<<dim3((BB*SS)/64, C1/128), 256, 0, stream>>>(
        points2, D2, W1c + D1, D1 + D2, P2h, C1,
        nullptr, nullptr, nullptr, nullptr, nullptr);

    // temp = points1 @ W1[:,:128]^T   (plain GEMM, fp32 out, no fusion)
    gemm_mfma_kernel<128, float, float, false, false>
        <<<dim3(MTOT/64, C1/128), 256, 0, stream>>>(
        points1, D1, W1c, D1 + D2, tempf, C1,
        nullptr, nullptr, nullptr, nullptr, nullptr);

    // y1 = temp + interp(P2) + b1  (f16 out) + BN1 stats from fp32
    interp_stats_kernel<<<MTOT/32, 256, 0, stream>>>(
        tempf, P2h, idx, w, b1, y1h, sum1, sq1);

    finalize_kernel<<<1, 256, 0, stream>>>(sum1, sq1, g1, beta1, MTOT, C1, scale1, shift1);

    // out = relu(bn1(y1)) @ W2^T + b2;  fp32 out; fused BN2 stats
    gemm_mfma_kernel<256, _Float16, float, true, true>
        <<<dim3(MTOT/64, C2/128), 256, 0, stream>>>(
        y1h, C1, W2c, C1, out, C2,
        b2, scale1, shift1, sum2, sq2);

    finalize_kernel<<<1, 128, 0, stream>>>(sum2, sq2, g2, beta2, MTOT, C2, scale2, shift2);
    bnrelu_kernel<<<(MTOT*C2/4)/256, 256, 0, stream>>>(out, MTOT*C2/4, C2, scale2, shift2);
}